// Round 1
// baseline (183.909 us; speedup 1.0000x reference)
//
#include <hip/hip_runtime.h>

// SSIM 3D on MI355X.
// Reference: five 5x5x5 "SAME" conv3d over x1=img1[:,1:2] and x2=img2,
// then SSIM map and 1 - mean. Window is rank-1 separable (constant along H),
// so we factorize it exactly on-device into u (D), v (H), t (W) and run a
// fused separable pipeline computing all 5 convolved fields at once.

#define NDIM 128
#define TW 16
#define TH 16
#define DSUB 32

__global__ void factorize_window(const float* __restrict__ w, float* __restrict__ ws) {
    // w is 5x5x5 (D,H,W), rank-1: w[i][j][k] = u[i]*v[j]*t[k]
    if (threadIdx.x == 0) {
        float w000 = w[0];
        #pragma unroll
        for (int i = 0; i < 5; ++i) ws[i]      = w[i * 25];
        #pragma unroll
        for (int j = 0; j < 5; ++j) ws[5 + j]  = w[j * 5] / w000;
        #pragma unroll
        for (int k = 0; k < 5; ++k) ws[10 + k] = w[k] / w000;
    }
}

__launch_bounds__(256, 4)
__global__ void ssim_main(const float* __restrict__ img1,
                          const float* __restrict__ img2,
                          const float* __restrict__ wfac,
                          float* __restrict__ partials) {
    // block decode: 8 W-tiles x 8 H-tiles x 4 D-chunks x 4 batches = 1024 blocks
    const int bid = blockIdx.x;
    const int tw = bid & 7;
    const int th = (bid >> 3) & 7;
    const int td = (bid >> 6) & 3;
    const int b  = bid >> 8;

    const int w0 = tw * TW, h0 = th * TH, d0 = td * DSUB;
    const float* __restrict__ x1 = img1 + (size_t)(b * 2 + 1) * NDIM * NDIM * NDIM; // channel 1
    const float* __restrict__ x2 = img2 + (size_t)b * NDIM * NDIM * NDIM;

    float uW[5], vW[5], tWt[5];
    #pragma unroll
    for (int i = 0; i < 5; ++i) { uW[i] = wfac[i]; vW[i] = wfac[5 + i]; tWt[i] = wfac[10 + i]; }

    __shared__ float sRaw1[20 * 21];       // raw slice + halo, stride 21 (bank pad)
    __shared__ float sRaw2[20 * 21];
    __shared__ float sWc[5 * 20 * 16];     // W-convolved 5 fields, 20 rows x 16 cols
    __shared__ float ring[5 * 5 * 256];    // depth ring: 5 slots x 5 fields x 256 pts
    __shared__ float sRed[4];

    const int tid = threadIdx.x;
    const int wc_ = tid & 15;
    const int hr_ = tid >> 4;

    float accS = 0.f;

    for (int d = d0 - 2; d <= d0 + DSUB + 1; ++d) {
        __syncthreads();  // guard sRaw/sWc/ring-slot overwrite vs previous iter reads
        const bool dv = (d >= 0) && (d < NDIM);
        // ---- stage raw slice (zero-padded halo) ----
        for (int p = tid; p < 400; p += 256) {
            const int hh = p / 20, ww = p - hh * 20;
            const int gh = h0 + hh - 2, gw = w0 + ww - 2;
            float a = 0.f, bb = 0.f;
            if (dv && (unsigned)gh < NDIM && (unsigned)gw < NDIM) {
                const size_t off = ((size_t)d * NDIM + gh) * NDIM + gw;
                a = x1[off];
                bb = x2[off];
            }
            sRaw1[hh * 21 + ww] = a;
            sRaw2[hh * 21 + ww] = bb;
        }
        __syncthreads();
        // ---- W-conv: 5 fields at 20 rows x 16 cols ----
        for (int p = tid; p < 320; p += 256) {
            const int hh = p >> 4, wc = p & 15;
            float m1 = 0.f, m2 = 0.f, q11 = 0.f, q22 = 0.f, q12 = 0.f;
            #pragma unroll
            for (int c = 0; c < 5; ++c) {
                const float a  = sRaw1[hh * 21 + wc + c];
                const float bb = sRaw2[hh * 21 + wc + c];
                const float wt = tWt[c];
                m1  += wt * a;
                m2  += wt * bb;
                q11 += wt * a * a;
                q22 += wt * bb * bb;
                q12 += wt * a * bb;
            }
            sWc[0 * 320 + p] = m1;
            sWc[1 * 320 + p] = m2;
            sWc[2 * 320 + p] = q11;
            sWc[3 * 320 + p] = q22;
            sWc[4 * 320 + p] = q12;
        }
        __syncthreads();
        // ---- H-conv into ring slot d mod 5 ----
        {
            int slot = d % 5; if (slot < 0) slot += 5;
            float a0 = 0.f, a1 = 0.f, a2 = 0.f, a3 = 0.f, a4 = 0.f;
            #pragma unroll
            for (int r = 0; r < 5; ++r) {
                const float vw = vW[r];
                const int base = (hr_ + r) * 16 + wc_;
                a0 += vw * sWc[0 * 320 + base];
                a1 += vw * sWc[1 * 320 + base];
                a2 += vw * sWc[2 * 320 + base];
                a3 += vw * sWc[3 * 320 + base];
                a4 += vw * sWc[4 * 320 + base];
            }
            float* rp = &ring[slot * 5 * 256 + tid];
            rp[0 * 256] = a0; rp[1 * 256] = a1; rp[2 * 256] = a2;
            rp[3 * 256] = a3; rp[4 * 256] = a4;
        }
        __syncthreads();
        // ---- D-conv + SSIM emit for dd = d-2 ----
        const int dd = d - 2;
        if (dd >= d0 && dd < d0 + DSUB) {
            float F0 = 0.f, F1 = 0.f, F2 = 0.f, F3 = 0.f, F4 = 0.f;
            #pragma unroll
            for (int s = 0; s < 5; ++s) {
                int sl = (dd - 2 + s) % 5; if (sl < 0) sl += 5;
                const float uw = uW[s];
                const float* rp = &ring[sl * 5 * 256 + tid];
                F0 += uw * rp[0 * 256];
                F1 += uw * rp[1 * 256];
                F2 += uw * rp[2 * 256];
                F3 += uw * rp[3 * 256];
                F4 += uw * rp[4 * 256];
            }
            const float C1 = 1e-4f;   // 0.01^2
            const float C2 = 9e-4f;   // 0.03^2
            const float mu1 = F0, mu2 = F1;
            const float mu1sq = mu1 * mu1, mu2sq = mu2 * mu2, mu12 = mu1 * mu2;
            const float s11 = F2 - mu1sq, s22 = F3 - mu2sq, s12 = F4 - mu12;
            const float num = (2.f * mu12 + C1) * (2.f * s12 + C2);
            const float den = (mu1sq + mu2sq + C1) * (s11 + s22 + C2);
            accS += num / den;
        }
    }

    // ---- block reduction -> one partial per block ----
    #pragma unroll
    for (int off = 32; off > 0; off >>= 1)
        accS += __shfl_down(accS, off, 64);
    __syncthreads();
    if ((tid & 63) == 0) sRed[tid >> 6] = accS;
    __syncthreads();
    if (tid == 0) partials[bid] = sRed[0] + sRed[1] + sRed[2] + sRed[3];
}

__global__ void finalize_kernel(const float* __restrict__ partials, float* __restrict__ out) {
    const int tid = threadIdx.x;
    double s = 0.0;
    for (int i = tid; i < 1024; i += 256) s += (double)partials[i];
    #pragma unroll
    for (int off = 32; off > 0; off >>= 1)
        s += __shfl_down(s, off, 64);
    __shared__ double sm[4];
    if ((tid & 63) == 0) sm[tid >> 6] = s;
    __syncthreads();
    if (tid == 0)
        out[0] = 1.0f - (float)((sm[0] + sm[1] + sm[2] + sm[3]) / (double)(4LL * 128 * 128 * 128));
}

extern "C" void kernel_launch(void* const* d_in, const int* in_sizes, int n_in,
                              void* d_out, int out_size, void* d_ws, size_t ws_size,
                              hipStream_t stream) {
    const float* img1 = (const float*)d_in[0];   // (4,2,128,128,128) fp32
    const float* img2 = (const float*)d_in[1];   // (4,1,128,128,128) fp32
    const float* win  = (const float*)d_in[2];   // (1,1,5,5,5) fp32
    float* out = (float*)d_out;                  // scalar fp32
    float* ws  = (float*)d_ws;
    float* wfac     = ws;        // 16 floats (u[5], v[5], t[5])
    float* partials = ws + 16;   // 1024 floats, fully rewritten every launch

    hipLaunchKernelGGL(factorize_window, dim3(1), dim3(64), 0, stream, win, wfac);
    hipLaunchKernelGGL(ssim_main, dim3(1024), dim3(256), 0, stream, img1, img2, wfac, partials);
    hipLaunchKernelGGL(finalize_kernel, dim3(1), dim3(256), 0, stream, partials, out);
}